// Round 1
// baseline (506.026 us; speedup 1.0000x reference)
//
#include <hip/hip_runtime.h>
#include <stdint.h>
#include <math.h>

typedef float fx4 __attribute__((ext_vector_type(4)));
typedef short sx8 __attribute__((ext_vector_type(8)));
typedef __bf16 bfx8 __attribute__((ext_vector_type(8)));
typedef unsigned short ux4 __attribute__((ext_vector_type(4)));

#define NB 4096
#define ND 1024
#define CEPS 1e-6f
#define CTHR 0.5f

// ---------- helpers ----------

__device__ __forceinline__ unsigned short f2bf(float f) {
  uint32_t u = __builtin_bit_cast(uint32_t, f);
  u = u + 0x7FFFu + ((u >> 16) & 1u);   // RNE
  return (unsigned short)(u >> 16);
}

__device__ __forceinline__ void gload16(const void* g, void* l) {
  __builtin_amdgcn_global_load_lds(
      (const __attribute__((address_space(1))) uint32_t*)(uintptr_t)g,
      (__attribute__((address_space(3))) uint32_t*)(uint32_t)(uintptr_t)l,
      16, 0, 0);
}

__device__ __forceinline__ bfx8 ldfrag(const unsigned short* p) {
  sx8 r = *(const sx8*)p;
  return __builtin_bit_cast(bfx8, r);
}

// ---------- kernel 1: f32 -> bf16 convert + row norms (f32) ----------

__global__ __launch_bounds__(256) void cmc_convert(
    const float* __restrict__ in, unsigned short* __restrict__ xb,
    float* __restrict__ lnorm) {
  const int row = blockIdx.x;           // 0 .. 3*4096-1
  const int tid = threadIdx.x;
  const fx4 v = *(const fx4*)(in + (size_t)row * ND + tid * 4);
  ux4 o;
  o[0] = f2bf(v[0]); o[1] = f2bf(v[1]); o[2] = f2bf(v[2]); o[3] = f2bf(v[3]);
  *(ux4*)(xb + (size_t)row * ND + tid * 4) = o;
  float ss = v[0]*v[0] + v[1]*v[1] + v[2]*v[2] + v[3]*v[3];
  #pragma unroll
  for (int d = 1; d < 64; d <<= 1) ss += __shfl_xor(ss, d);
  __shared__ float sred[4];
  if ((tid & 63) == 0) sred[tid >> 6] = ss;
  __syncthreads();
  if (tid == 0) lnorm[row] = sqrtf(sred[0] + sred[1] + sred[2] + sred[3]);
}

// ---------- gram K-loop: acc[4][4] (64x64 per wave, 128x128 per block) ----------

__device__ __forceinline__ void gram_1024(
    const unsigned short* __restrict__ Arows,
    const unsigned short* __restrict__ Brows,
    int arow0, int brow0,
    unsigned short* As, unsigned short* Bs,
    int tid, int lane, int wr, int wc,
    fx4 acc[4][4]) {
  fx4 z = {0.f, 0.f, 0.f, 0.f};
  #pragma unroll
  for (int m = 0; m < 4; ++m)
    #pragma unroll
    for (int n = 0; n < 4; ++n) acc[m][n] = z;

  const int sr = tid >> 2;              // 0..63 staging row
  const int sc = (tid & 3) * 8;         // staging col (elements)
  const unsigned short* ga = Arows + (size_t)(arow0 + sr) * ND + sc;
  const unsigned short* gb = Brows + (size_t)(brow0 + sr) * ND + sc;
  unsigned short* la0 = As + sr * 32 + sc;
  unsigned short* la1 = As + (sr + 64) * 32 + sc;
  unsigned short* lb0 = Bs + sr * 32 + sc;
  unsigned short* lb1 = Bs + (sr + 64) * 32 + sc;
  const int foff = (lane & 15) * 32 + (lane >> 4) * 8;   // fragment base (elements)

  for (int k0 = 0; k0 < ND; k0 += 32) {
    gload16(ga + k0, la0);
    gload16(ga + (size_t)64 * ND + k0, la1);
    gload16(gb + k0, lb0);
    gload16(gb + (size_t)64 * ND + k0, lb1);
    __syncthreads();                    // drains vmcnt before barrier
    bfx8 af[4], bf[4];
    #pragma unroll
    for (int m = 0; m < 4; ++m) af[m] = ldfrag(As + (wr * 64 + m * 16) * 32 + foff);
    #pragma unroll
    for (int n = 0; n < 4; ++n) bf[n] = ldfrag(Bs + (wc * 64 + n * 16) * 32 + foff);
    #pragma unroll
    for (int m = 0; m < 4; ++m)
      #pragma unroll
      for (int n = 0; n < 4; ++n)
        acc[m][n] = __builtin_amdgcn_mfma_f32_16x16x32_bf16(af[m], bf[n], acc[m][n], 0, 0, 0);
    __syncthreads();                    // protect LDS before next staging
  }
}

// ---------- kernel 2: per-pair fused cross + s1 + s2 + masked exp row-partials ----------

__global__ __launch_bounds__(256, 2) void cmc_pair(
    const unsigned short* __restrict__ xb, const float* __restrict__ lnorm,
    float* __restrict__ sumexp, float* __restrict__ cntrow,
    float* __restrict__ diagv) {
  __shared__ unsigned short As[128 * 32];
  __shared__ unsigned short Bs[128 * 32];
  __shared__ float Lri[128], Lrj[128], Lci[128], Lcj[128];

  const int p = blockIdx.z;                  // pair: 0->(0,1) 1->(0,2) 2->(1,2)
  const int mi = (p == 2) ? 1 : 0;
  const int mj = (p == 0) ? 1 : 2;
  const int rb = blockIdx.y * 128;
  const int cb = blockIdx.x * 128;
  const int tid = threadIdx.x;
  const int lane = tid & 63;
  const int w = tid >> 6;
  const int wr = w >> 1, wc = w & 1;

  const unsigned short* Xi = xb + (size_t)mi * NB * ND;
  const unsigned short* Xj = xb + (size_t)mj * NB * ND;
  const float* li = lnorm + mi * NB;
  const float* lj = lnorm + mj * NB;

  if (tid < 128) {
    Lri[tid] = li[rb + tid]; Lrj[tid] = lj[rb + tid];
    Lci[tid] = li[cb + tid]; Lcj[tid] = lj[cb + tid];
  }
  // (barrier provided inside first gram_1024 before any epilogue read)

  fx4 acc_c[4][4], acc_s[4][4];

  // cross = Xi[rb] . Xj[cb]^T
  gram_1024(Xi, Xj, rb, cb, As, Bs, tid, lane, wr, wc, acc_c);
  // s1 = Xi[rb] . Xi[cb]^T  -> pack mask bits
  gram_1024(Xi, Xi, rb, cb, As, Bs, tid, lane, wr, wc, acc_s);

  uint64_t bits = 0ull;
  #pragma unroll
  for (int m = 0; m < 4; ++m)
    #pragma unroll
    for (int n = 0; n < 4; ++n)
      #pragma unroll
      for (int r4 = 0; r4 < 4; ++r4) {
        const int rl = wr * 64 + m * 16 + ((lane >> 4) << 2) + r4;
        const int cl = wc * 64 + n * 16 + (lane & 15);
        const float cv = acc_s[m][n][r4] / fmaxf(Lri[rl] * Lci[cl], CEPS);
        if (cv <= CTHR) bits |= (1ull << (m * 16 + n * 4 + r4));
      }

  // s2 = Xj[rb] . Xj[cb]^T
  gram_1024(Xj, Xj, rb, cb, As, Bs, tid, lane, wr, wc, acc_s);

  // fused epilogue: mask, exp, row partial sums + counts, diag
  #pragma unroll
  for (int m = 0; m < 4; ++m)
    #pragma unroll
    for (int r4 = 0; r4 < 4; ++r4) {
      const int rl = wr * 64 + m * 16 + ((lane >> 4) << 2) + r4;
      const int rg = rb + rl;
      float se = 0.f, ct = 0.f;
      #pragma unroll
      for (int n = 0; n < 4; ++n) {
        const int cl = wc * 64 + n * 16 + (lane & 15);
        const int cg = cb + cl;
        const bool b1 = (bits >> (m * 16 + n * 4 + r4)) & 1ull;
        const float s2c = acc_s[m][n][r4] / fmaxf(Lrj[rl] * Lcj[cl], CEPS);
        const bool msk = b1 || (s2c <= CTHR) || (rg == cg);
        const float logit = acc_c[m][n][r4] / fmaxf(Lri[rl] * Lcj[cl], CEPS) / 0.1f;
        if (rg == cg) diagv[p * NB + rg] = logit;
        if (msk) { se += __expf(logit); ct += 1.f; }
      }
      #pragma unroll
      for (int d0 = 1; d0 < 16; d0 <<= 1) {
        se += __shfl_xor(se, d0);
        ct += __shfl_xor(ct, d0);
      }
      if ((lane & 15) == 0) {
        atomicAdd(&sumexp[p * NB + rg], se);
        atomicAdd(&cntrow[p * NB + rg], ct);
      }
    }
}

// ---------- kernel 3: finalize ----------

__global__ __launch_bounds__(256) void cmc_final(
    const float* __restrict__ sumexp, const float* __restrict__ cntrow,
    const float* __restrict__ diagv, float* __restrict__ out) {
  const int tid = threadIdx.x;
  __shared__ float sred[8];
  float lsum = 0.f;
  for (int p = 0; p < 3; ++p) {
    float t = 0.f, c = 0.f;
    for (int r = tid; r < NB; r += 256) {
      const float cnt = cntrow[p * NB + r];
      if (cnt > 1.0f) {
        t += logf(sumexp[p * NB + r]) - diagv[p * NB + r];
        c += 1.f;
      }
    }
    #pragma unroll
    for (int d = 1; d < 64; d <<= 1) { t += __shfl_xor(t, d); c += __shfl_xor(c, d); }
    if ((tid & 63) == 0) { sred[(tid >> 6) * 2] = t; sred[(tid >> 6) * 2 + 1] = c; }
    __syncthreads();
    if (tid == 0) {
      const float tt = sred[0] + sred[2] + sred[4] + sred[6];
      const float cc = sred[1] + sred[3] + sred[5] + sred[7];
      lsum += (cc > 0.f) ? tt / fmaxf(cc, 1.f) : 0.f;
    }
    __syncthreads();
  }
  if (tid == 0) out[0] = lsum / 3.0f;
}

// ---------- launch ----------

extern "C" void kernel_launch(void* const* d_in, const int* in_sizes, int n_in,
                              void* d_out, int out_size, void* d_ws, size_t ws_size,
                              hipStream_t stream) {
  const float* in = (const float*)d_in[0];
  float* out = (float*)d_out;
  char* ws = (char*)d_ws;

  const size_t XB_BYTES = (size_t)3 * NB * ND * sizeof(unsigned short); // 25,165,824
  unsigned short* xb = (unsigned short*)ws;
  float* lnorm  = (float*)(ws + XB_BYTES);
  float* sumexp = lnorm + 3 * NB;
  float* cntrow = sumexp + 3 * NB;
  float* diagv  = cntrow + 3 * NB;

  // zero the atomically-accumulated per-row buffers (sumexp + cntrow contiguous)
  hipMemsetAsync(sumexp, 0, (size_t)2 * 3 * NB * sizeof(float), stream);

  cmc_convert<<<3 * NB, 256, 0, stream>>>(in, xb, lnorm);
  cmc_pair<<<dim3(NB / 128, NB / 128, 3), 256, 0, stream>>>(xb, lnorm, sumexp, cntrow, diagv);
  cmc_final<<<1, 256, 0, stream>>>(sumexp, cntrow, diagv, out);
}

// Round 2
// 303.728 us; speedup vs baseline: 1.6661x; 1.6661x over previous
//
#include <hip/hip_runtime.h>
#include <stdint.h>
#include <math.h>

typedef float fx4 __attribute__((ext_vector_type(4)));
typedef short sx8 __attribute__((ext_vector_type(8)));
typedef __bf16 bfx8 __attribute__((ext_vector_type(8)));
typedef unsigned short ux4 __attribute__((ext_vector_type(4)));

#define NB 4096
#define ND 1024
#define CEPS 1e-6f
#define CTHR 0.5f

// ---------- helpers ----------

__device__ __forceinline__ unsigned short f2bf(float f) {
  uint32_t u = __builtin_bit_cast(uint32_t, f);
  u = u + 0x7FFFu + ((u >> 16) & 1u);   // RNE
  return (unsigned short)(u >> 16);
}

__device__ __forceinline__ void gload16(const void* g, void* l) {
  __builtin_amdgcn_global_load_lds(
      (const __attribute__((address_space(1))) uint32_t*)(uintptr_t)g,
      (__attribute__((address_space(3))) uint32_t*)(uint32_t)(uintptr_t)l,
      16, 0, 0);
}

__device__ __forceinline__ bfx8 ldfrag(const unsigned short* p) {
  sx8 r = *(const sx8*)p;
  return __builtin_bit_cast(bfx8, r);
}

// ---------- kernel 1: f32 -> bf16 convert + row norms (f32) ----------

__global__ __launch_bounds__(256) void cmc_convert(
    const float* __restrict__ in, unsigned short* __restrict__ xb,
    float* __restrict__ lnorm) {
  const int row = blockIdx.x;           // 0 .. 3*4096-1
  const int tid = threadIdx.x;
  const fx4 v = *(const fx4*)(in + (size_t)row * ND + tid * 4);
  ux4 o;
  o[0] = f2bf(v[0]); o[1] = f2bf(v[1]); o[2] = f2bf(v[2]); o[3] = f2bf(v[3]);
  *(ux4*)(xb + (size_t)row * ND + tid * 4) = o;
  float ss = v[0]*v[0] + v[1]*v[1] + v[2]*v[2] + v[3]*v[3];
  #pragma unroll
  for (int d = 1; d < 64; d <<= 1) ss += __shfl_xor(ss, d);
  __shared__ float sred[4];
  if ((tid & 63) == 0) sred[tid >> 6] = ss;
  __syncthreads();
  if (tid == 0) lnorm[row] = sqrtf(sred[0] + sred[1] + sred[2] + sred[3]);
}

// ---------- gram K-loop: acc[4][4] (64x64 per wave, 128x128 per block) ----------

__device__ __forceinline__ void gram_1024(
    const unsigned short* __restrict__ Arows,
    const unsigned short* __restrict__ Brows,
    int arow0, int brow0,
    unsigned short* As, unsigned short* Bs,
    int tid, int lane, int wr, int wc,
    fx4 acc[4][4]) {
  fx4 z = {0.f, 0.f, 0.f, 0.f};
  #pragma unroll
  for (int m = 0; m < 4; ++m)
    #pragma unroll
    for (int n = 0; n < 4; ++n) acc[m][n] = z;

  const int sr = tid >> 2;              // 0..63 staging row
  const int sc = (tid & 3) * 8;         // staging col (elements)
  const unsigned short* ga = Arows + (size_t)(arow0 + sr) * ND + sc;
  const unsigned short* gb = Brows + (size_t)(brow0 + sr) * ND + sc;
  unsigned short* la0 = As + sr * 32 + sc;
  unsigned short* la1 = As + (sr + 64) * 32 + sc;
  unsigned short* lb0 = Bs + sr * 32 + sc;
  unsigned short* lb1 = Bs + (sr + 64) * 32 + sc;
  const int foff = (lane & 15) * 32 + (lane >> 4) * 8;   // fragment base (elements)

  for (int k0 = 0; k0 < ND; k0 += 32) {
    gload16(ga + k0, la0);
    gload16(ga + (size_t)64 * ND + k0, la1);
    gload16(gb + k0, lb0);
    gload16(gb + (size_t)64 * ND + k0, lb1);
    __syncthreads();                    // drains vmcnt before barrier
    bfx8 af[4], bf[4];
    #pragma unroll
    for (int m = 0; m < 4; ++m) af[m] = ldfrag(As + (wr * 64 + m * 16) * 32 + foff);
    #pragma unroll
    for (int n = 0; n < 4; ++n) bf[n] = ldfrag(Bs + (wc * 64 + n * 16) * 32 + foff);
    #pragma unroll
    for (int m = 0; m < 4; ++m)
      #pragma unroll
      for (int n = 0; n < 4; ++n)
        acc[m][n] = __builtin_amdgcn_mfma_f32_16x16x32_bf16(af[m], bf[n], acc[m][n], 0, 0, 0);
    __syncthreads();                    // protect LDS before next staging
  }
}

// ---------- kernel 2: per-modal self-gram -> bitmask (upper-tri + transpose) ----------

__global__ __launch_bounds__(256, 2) void cmc_selfmask(
    const unsigned short* __restrict__ xb, const float* __restrict__ lnorm,
    uint32_t* __restrict__ maskw) {
  __shared__ __align__(16) unsigned short As[128 * 32];
  __shared__ __align__(16) unsigned short Bs[128 * 32];
  __shared__ float Lr[128], Lc[128];

  const int md = blockIdx.z;
  const int bx = blockIdx.x, by = blockIdx.y;
  if (by > bx) return;                  // symmetric: skip lower triangle
  const int rb = by * 128, cb = bx * 128;
  const int tid = threadIdx.x;
  const int lane = tid & 63;
  const int w = tid >> 6;
  const int wr = w >> 1, wc = w & 1;

  const unsigned short* X = xb + (size_t)md * NB * ND;
  if (tid < 128) {
    Lr[tid] = lnorm[md * NB + rb + tid];
    Lc[tid] = lnorm[md * NB + cb + tid];
  }

  fx4 acc[4][4];
  gram_1024(X, X, rb, cb, As, Bs, tid, lane, wr, wc, acc);

  // threshold -> 128x128 bit tile in LDS (reuse As; last gram op was syncthreads)
  uint32_t* tile = (uint32_t*)As;       // [128][4] words
  const int g = lane >> 4;
  #pragma unroll
  for (int m = 0; m < 4; ++m)
    #pragma unroll
    for (int r4 = 0; r4 < 4; ++r4) {
      const int rl = wr * 64 + m * 16 + (g << 2) + r4;
      uint64_t b[4];
      #pragma unroll
      for (int n = 0; n < 4; ++n) {
        const int cl = wc * 64 + n * 16 + (lane & 15);
        const float cv = acc[m][n][r4] / fmaxf(Lr[rl] * Lc[cl], CEPS);
        b[n] = __ballot(cv <= CTHR);
      }
      if ((lane & 15) == 0) {
        const uint32_t w0 = (uint32_t)((b[0] >> (16 * g)) & 0xFFFF) |
                            ((uint32_t)((b[1] >> (16 * g)) & 0xFFFF) << 16);
        const uint32_t w1 = (uint32_t)((b[2] >> (16 * g)) & 0xFFFF) |
                            ((uint32_t)((b[3] >> (16 * g)) & 0xFFFF) << 16);
        tile[rl * 4 + wc * 2]     = w0;
        tile[rl * 4 + wc * 2 + 1] = w1;
      }
    }
  __syncthreads();

  // direct region: rows [rb,rb+128) x words [cb/32, +4) — exclusively owned
  for (int t = tid; t < 512; t += 256) {
    const int row = t >> 2, wd = t & 3;
    maskw[((size_t)md * NB + rb + row) * 128 + (cb >> 5) + wd] = tile[t];
  }
  // transposed region: rows [cb,cb+128) x words [rb/32, +4)
  if (by != bx) {
    for (int t = tid; t < 512; t += 256) {
      const int crow = t & 127;         // transposed-output local row (= local col)
      const int wp = t >> 7;            // which 32-row word
      uint32_t wv = 0;
      #pragma unroll
      for (int r = 0; r < 32; ++r) {
        const uint32_t bit = (tile[(wp * 32 + r) * 4 + (crow >> 5)] >> (crow & 31)) & 1u;
        wv |= bit << r;
      }
      maskw[((size_t)md * NB + cb + crow) * 128 + (rb >> 5) + wp] = wv;
    }
  }
}

// ---------- kernel 3: per-pair cross gram + masked exp row-partials ----------

__global__ __launch_bounds__(256, 2) void cmc_pair(
    const unsigned short* __restrict__ xb, const float* __restrict__ lnorm,
    const uint32_t* __restrict__ maskw,
    float* __restrict__ sumexp, float* __restrict__ cntrow,
    float* __restrict__ diagv) {
  __shared__ __align__(16) unsigned short As[128 * 32];
  __shared__ __align__(16) unsigned short Bs[128 * 32];
  __shared__ float Lri[128], Lcj[128];

  const int p = blockIdx.z;                  // pair: 0->(0,1) 1->(0,2) 2->(1,2)
  const int mi = (p == 2) ? 1 : 0;
  const int mj = (p == 0) ? 1 : 2;
  const int rb = blockIdx.y * 128;
  const int cb = blockIdx.x * 128;
  const int tid = threadIdx.x;
  const int lane = tid & 63;
  const int w = tid >> 6;
  const int wr = w >> 1, wc = w & 1;

  const unsigned short* Xi = xb + (size_t)mi * NB * ND;
  const unsigned short* Xj = xb + (size_t)mj * NB * ND;

  if (tid < 128) {
    Lri[tid] = lnorm[mi * NB + rb + tid];
    Lcj[tid] = lnorm[mj * NB + cb + tid];
  }

  fx4 acc[4][4];
  gram_1024(Xi, Xj, rb, cb, As, Bs, tid, lane, wr, wc, acc);

  // stage the two mask tiles into LDS (reuse As): Mi[512] ++ Mj[512] words
  uint32_t* Mt = (uint32_t*)As;
  for (int t = tid; t < 512; t += 256) {
    const int row = t >> 2, wd = t & 3;
    Mt[t]       = maskw[((size_t)mi * NB + rb + row) * 128 + (cb >> 5) + wd];
    Mt[512 + t] = maskw[((size_t)mj * NB + rb + row) * 128 + (cb >> 5) + wd];
  }
  __syncthreads();

  // fused epilogue: mask, exp, row partial sums + counts, diag
  #pragma unroll
  for (int m = 0; m < 4; ++m)
    #pragma unroll
    for (int r4 = 0; r4 < 4; ++r4) {
      const int rl = wr * 64 + m * 16 + ((lane >> 4) << 2) + r4;
      const int rg = rb + rl;
      float se = 0.f, ct = 0.f;
      #pragma unroll
      for (int n = 0; n < 4; ++n) {
        const int cl = wc * 64 + n * 16 + (lane & 15);
        const int cg = cb + cl;
        const int widx = rl * 4 + (cl >> 5);
        const uint32_t bi = (Mt[widx] >> (cl & 31)) & 1u;
        const uint32_t bj = (Mt[512 + widx] >> (cl & 31)) & 1u;
        const bool msk = bi | bj | (rg == cg);
        const float logit = acc[m][n][r4] / fmaxf(Lri[rl] * Lcj[cl], CEPS) / 0.1f;
        if (rg == cg) diagv[p * NB + rg] = logit;
        if (msk) { se += __expf(logit); ct += 1.f; }
      }
      #pragma unroll
      for (int d0 = 1; d0 < 16; d0 <<= 1) {
        se += __shfl_xor(se, d0);
        ct += __shfl_xor(ct, d0);
      }
      if ((lane & 15) == 0) {
        atomicAdd(&sumexp[p * NB + rg], se);
        atomicAdd(&cntrow[p * NB + rg], ct);
      }
    }
}

// ---------- kernel 4: finalize ----------

__global__ __launch_bounds__(256) void cmc_final(
    const float* __restrict__ sumexp, const float* __restrict__ cntrow,
    const float* __restrict__ diagv, float* __restrict__ out) {
  const int tid = threadIdx.x;
  __shared__ float sred[8];
  float lsum = 0.f;
  for (int p = 0; p < 3; ++p) {
    float t = 0.f, c = 0.f;
    for (int r = tid; r < NB; r += 256) {
      const float cnt = cntrow[p * NB + r];
      if (cnt > 1.0f) {
        t += logf(sumexp[p * NB + r]) - diagv[p * NB + r];
        c += 1.f;
      }
    }
    #pragma unroll
    for (int d = 1; d < 64; d <<= 1) { t += __shfl_xor(t, d); c += __shfl_xor(c, d); }
    if ((tid & 63) == 0) { sred[(tid >> 6) * 2] = t; sred[(tid >> 6) * 2 + 1] = c; }
    __syncthreads();
    if (tid == 0) {
      const float tt = sred[0] + sred[2] + sred[4] + sred[6];
      const float cc = sred[1] + sred[3] + sred[5] + sred[7];
      lsum += (cc > 0.f) ? tt / fmaxf(cc, 1.f) : 0.f;
    }
    __syncthreads();
  }
  if (tid == 0) out[0] = lsum / 3.0f;
}

// ---------- launch ----------

extern "C" void kernel_launch(void* const* d_in, const int* in_sizes, int n_in,
                              void* d_out, int out_size, void* d_ws, size_t ws_size,
                              hipStream_t stream) {
  const float* in = (const float*)d_in[0];
  float* out = (float*)d_out;
  char* ws = (char*)d_ws;

  const size_t XB_BYTES = (size_t)3 * NB * ND * sizeof(unsigned short); // 25,165,824
  unsigned short* xb = (unsigned short*)ws;
  float* lnorm  = (float*)(ws + XB_BYTES);
  float* sumexp = lnorm + 3 * NB;
  float* cntrow = sumexp + 3 * NB;
  float* diagv  = cntrow + 3 * NB;
  uint32_t* maskw = (uint32_t*)(diagv + 3 * NB);   // [3][4096][128] words = 6 MB

  // zero the atomically-accumulated per-row buffers (sumexp + cntrow contiguous)
  hipMemsetAsync(sumexp, 0, (size_t)2 * 3 * NB * sizeof(float), stream);

  cmc_convert<<<3 * NB, 256, 0, stream>>>(in, xb, lnorm);
  cmc_selfmask<<<dim3(NB / 128, NB / 128, 3), 256, 0, stream>>>(xb, lnorm, maskw);
  cmc_pair<<<dim3(NB / 128, NB / 128, 3), 256, 0, stream>>>(xb, lnorm, maskw, sumexp, cntrow, diagv);
  cmc_final<<<1, 256, 0, stream>>>(sumexp, cntrow, diagv, out);
}